// Round 5
// baseline (917.862 us; speedup 1.0000x reference)
//
#include <hip/hip_runtime.h>

// DiffMoE fused step, MI355X gfx950. Round 5.
// Changes vs R4: ALL GEMM operands in brick layout. Brick(m16,k32) = 64
// lanes x 8 bf16: lane l holds M[m16*16+(l&15)][k32*32+(l>>4)*8 ..+8].
//  - Weights: pack_b (as R4).
//  - Activations: gating writes xh bricks, ln_gather writes Y bricks,
//    fc1 epilogue writes H1 bricks (for fc2).
//  - GEMM K-loop = 4 glds16/wave (1 brick each) + barrier + 8 linear
//    ds_read_b128 + 16 MFMA + barrier. One latency-drain point per iter,
//    no global->VGPR operand loads, no bank conflicts, low VGPR.

#define BS_   8192
#define D_    1024
#define DD_   4096
#define NEXP  8
#define KCAP  1024

typedef unsigned int   uint32;
typedef unsigned short u16;
typedef __bf16 bf16x8  __attribute__((ext_vector_type(8)));
typedef float  f32x4   __attribute__((ext_vector_type(4)));
typedef u16    u16x8   __attribute__((ext_vector_type(8)));
typedef u16    u16x4   __attribute__((ext_vector_type(4)));

__device__ __forceinline__ u16 f2bf(float f){
  uint32 u = __float_as_uint(f);
  u = (u + 0x7fffu + ((u >> 16) & 1u)) >> 16;   // RNE
  return (u16)u;
}
__device__ __forceinline__ float bf_lo(uint32 u){ return __uint_as_float(u << 16); }
__device__ __forceinline__ float bf_hi(uint32 u){ return __uint_as_float(u & 0xffff0000u); }

__device__ __forceinline__ float gelu_fast(float v){
  const float u2 = v * (1.5957691216057308f + 0.07135481282962162f * v * v);
  const float e  = __expf(u2);
  return v - v / (1.0f + e);
}
__device__ __forceinline__ void glds16(const u16* g, u16* l){
  __builtin_amdgcn_global_load_lds(
      (const __attribute__((address_space(1))) unsigned int*)g,
      (__attribute__((address_space(3))) unsigned int*)l, 16, 0, 0);
}

// ---------------------------------------------------------------- pack B ----
// fp32 [Nrows][K] -> bf16 bricks. kshift = log2(K/32).
__global__ __launch_bounds__(256)
void pack_b_kernel(const float* __restrict__ in, u16* __restrict__ out,
                   int K, int kshift)
{
  const long long t = (long long)blockIdx.x * 256 + threadIdx.x;
  const int  lane  = (int)(t & 63);
  const long long brick = t >> 6;
  const long long n16 = brick >> kshift;
  const int  k32  = (int)(brick & ((1 << kshift) - 1));
  const float* src = in + (n16 * 16 + (lane & 15)) * (long long)K
                        + k32 * 32 + (lane >> 4) * 8;
  const float4 a = *(const float4*)src;
  const float4 b = *(const float4*)(src + 4);
  u16x8 o;
  o[0]=f2bf(a.x); o[1]=f2bf(a.y); o[2]=f2bf(a.z); o[3]=f2bf(a.w);
  o[4]=f2bf(b.x); o[5]=f2bf(b.y); o[6]=f2bf(b.z); o[7]=f2bf(b.w);
  *(u16x8*)(out + t * 8) = o;
}

// ---------------------------------------------------------------- gating ----
// scores + keep_bits init + xh in BRICK layout (nk32 = 32).
// Row i, lane l holds cols l*16..+15 -> brick (i>>4)*32+(l>>1),
// quads (l&1)*2 and (l&1)*2+1, lane-row i&15.
__global__ __launch_bounds__(64)
void gating_kernel(const float* __restrict__ x, const float* __restrict__ Wg,
                   float* __restrict__ scores, uint32* __restrict__ keep_bits,
                   u16* __restrict__ xh)
{
  const int i    = blockIdx.x;
  const int lane = threadIdx.x;
  const float* xr = x + (size_t)i * D_ + lane * 16;
  const float4 x0 = *(const float4*)(xr +  0);
  const float4 x1 = *(const float4*)(xr +  4);
  const float4 x2 = *(const float4*)(xr +  8);
  const float4 x3 = *(const float4*)(xr + 12);
  u16x8 p0, p1;
  p0[0]=f2bf(x0.x); p0[1]=f2bf(x0.y); p0[2]=f2bf(x0.z); p0[3]=f2bf(x0.w);
  p0[4]=f2bf(x1.x); p0[5]=f2bf(x1.y); p0[6]=f2bf(x1.z); p0[7]=f2bf(x1.w);
  p1[0]=f2bf(x2.x); p1[1]=f2bf(x2.y); p1[2]=f2bf(x2.z); p1[3]=f2bf(x2.w);
  p1[4]=f2bf(x3.x); p1[5]=f2bf(x3.y); p1[6]=f2bf(x3.z); p1[7]=f2bf(x3.w);
  u16* dst = xh + ((size_t)(i >> 4) * 32 + (lane >> 1)) * 512
                + (lane & 1) * 256 + (i & 15) * 8;
  *(u16x8*)dst         = p0;
  *(u16x8*)(dst + 128) = p1;

  float acc[NEXP];
  #pragma unroll
  for (int e = 0; e < NEXP; e++){
    const float* wr = Wg + e * D_ + lane * 16;
    const float4 w0 = *(const float4*)(wr +  0);
    const float4 w1 = *(const float4*)(wr +  4);
    const float4 w2 = *(const float4*)(wr +  8);
    const float4 w3 = *(const float4*)(wr + 12);
    float s = x0.x*w0.x + x0.y*w0.y + x0.z*w0.z + x0.w*w0.w;
    s += x1.x*w1.x + x1.y*w1.y + x1.z*w1.z + x1.w*w1.w;
    s += x2.x*w2.x + x2.y*w2.y + x2.z*w2.z + x2.w*w2.w;
    s += x3.x*w3.x + x3.y*w3.y + x3.z*w3.z + x3.w*w3.w;
    acc[e] = s;
  }
  #pragma unroll
  for (int e = 0; e < NEXP; e++){
    #pragma unroll
    for (int off = 32; off >= 1; off >>= 1) acc[e] += __shfl_xor(acc[e], off);
  }
  if (lane == 0){
    #pragma unroll
    for (int e = 0; e < NEXP; e++) scores[i * NEXP + e] = (tanhf(acc[e]) + 1.0f) * 0.5f;
    keep_bits[i] = 0u;
  }
}

// ------------------------------------------------------------- selection ----
__global__ __launch_bounds__(256)
void select_kernel(const float* __restrict__ scores, uint32* __restrict__ keep_bits,
                   int* __restrict__ counts, int* __restrict__ rowlist,
                   float* __restrict__ wlist, int* __restrict__ inv)
{
  __shared__ unsigned long long sk[2048];
  const int e = blockIdx.y;
  const int i = blockIdx.x * 256 + threadIdx.x;
  const float ms = scores[i * NEXP + e];
  const unsigned long long mk =
      ((unsigned long long)__float_as_uint(ms) << 32) | (uint32)(BS_ - 1 - i);
  int cnt = 0;
  for (int base = 0; base < BS_; base += 2048){
    #pragma unroll
    for (int u = 0; u < 8; u++){
      const int j = base + (int)threadIdx.x * 8 + u;
      const float sj = scores[j * NEXP + e];
      sk[threadIdx.x * 8 + u] =
          ((unsigned long long)__float_as_uint(sj) << 32) | (uint32)(BS_ - 1 - j);
    }
    __syncthreads();
    #pragma unroll 8
    for (int jj = 0; jj < 2048; jj++) cnt += (sk[jj] > mk) ? 1 : 0;
    __syncthreads();
  }
  if (cnt < KCAP){
    const int slot = atomicAdd(&counts[e], 1);
    rowlist[e * KCAP + slot] = i;
    wlist[e * KCAP + slot]   = ms;
    inv[i * NEXP + e]        = slot;
    atomicOr(&keep_bits[i], 1u << e);
  }
}

// ------------------------------------------------------------------ GEMM ----
// C[m][n] = sum_k A[m][k]*B[n][k], A and B both brick-packed bf16.
// MODE 0: +bias, gelu, bf16 row-major out (cp -> loss).
// MODE 1: +bias, gelu, bf16 BRICK out (fc1 -> H1 for fc2).
// MODE 2: split-K fp32 partials row-major to P0/P1, no bias (fc2).
template<int MODE, int SPLIT>
__global__ __launch_bounds__(256)
void gemm_br(const u16* __restrict__ A, const u16* __restrict__ B,
             const float* __restrict__ bias, void* __restrict__ Cv,
             float* __restrict__ P0, float* __restrict__ P1,
             int M, int N, int K,
             long long sA, long long sB, long long sBias, long long sC)
{
  __shared__ u16 smA[8 * 512];
  __shared__ u16 smB[8 * 512];
  const int zr   = blockIdx.z;
  const int z    = zr / SPLIT, ks = zr % SPLIT;
  const int nk   = K >> 5;
  const int kIt0 = (nk / SPLIT) * ks, kIt1 = kIt0 + nk / SPLIT;
  const int m0   = blockIdx.y * 128;
  const int n0   = blockIdx.x * 128;
  const int tid  = threadIdx.x;
  const int lane = tid & 63, wv = tid >> 6;
  const int l15  = lane & 15, quad = lane >> 4;
  const int moff = (wv >> 1) * 64, noff = (wv & 1) * 64;

  const u16* Apk = A + (long long)z * sA + (long long)((m0 >> 4) + wv * 2) * nk * 512 + lane * 8;
  const u16* Bpk = B + (long long)z * sB + (long long)((n0 >> 4) + wv * 2) * nk * 512 + lane * 8;
  const long long nstr = (long long)nk * 512;   // u16 per brick-row (16 m)

  f32x4 acc[4][4];
  #pragma unroll
  for (int i = 0; i < 4; i++)
    #pragma unroll
    for (int j = 0; j < 4; j++)
      acc[i][j] = (f32x4){0.f, 0.f, 0.f, 0.f};

  for (int kk = kIt0; kk < kIt1; kk++){
    glds16(Apk +         (long long)kk * 512, smA + (wv * 2    ) * 512);
    glds16(Apk + nstr +  (long long)kk * 512, smA + (wv * 2 + 1) * 512);
    glds16(Bpk +         (long long)kk * 512, smB + (wv * 2    ) * 512);
    glds16(Bpk + nstr +  (long long)kk * 512, smB + (wv * 2 + 1) * 512);
    __syncthreads();
    bf16x8 aF[4], bF[4];
    #pragma unroll
    for (int i = 0; i < 4; i++)
      aF[i] = *(const bf16x8*)(smA + ((wv >> 1) * 4 + i) * 512 + lane * 8);
    #pragma unroll
    for (int j = 0; j < 4; j++)
      bF[j] = *(const bf16x8*)(smB + ((wv & 1) * 4 + j) * 512 + lane * 8);
    #pragma unroll
    for (int i = 0; i < 4; i++)
      #pragma unroll
      for (int j = 0; j < 4; j++)
        acc[i][j] = __builtin_amdgcn_mfma_f32_16x16x32_bf16(bF[j], aF[i], acc[i][j], 0, 0, 0);
    __syncthreads();
  }

  // D^T mapping: acc[i][j] reg r -> (m = m0+moff+i*16+l15, n = n0+noff+j*16+quad*4+r)
  if constexpr (MODE == 2){
    float* Pout = (ks == 0 ? P0 : P1) + (long long)z * sC;
    #pragma unroll
    for (int i = 0; i < 4; i++){
      const int gm = m0 + moff + i * 16 + l15;
      #pragma unroll
      for (int j = 0; j < 4; j++){
        const int gn = n0 + noff + j * 16 + quad * 4;
        *(float4*)(Pout + (long long)gm * N + gn) =
            make_float4(acc[i][j][0], acc[i][j][1], acc[i][j][2], acc[i][j][3]);
      }
    }
  } else {
    const float* biasp = bias + (long long)z * sBias;
    const long long cbase = (long long)z * sC;
    const int nkO = N >> 5;
    #pragma unroll
    for (int i = 0; i < 4; i++){
      const int gm = m0 + moff + i * 16 + l15;
      #pragma unroll
      for (int j = 0; j < 4; j++){
        const int gn = n0 + noff + j * 16 + quad * 4;
        const float4 bv = *(const float4*)(biasp + gn);
        float v0 = gelu_fast(acc[i][j][0] + bv.x);
        float v1 = gelu_fast(acc[i][j][1] + bv.y);
        float v2 = gelu_fast(acc[i][j][2] + bv.z);
        float v3 = gelu_fast(acc[i][j][3] + bv.w);
        u16x4 o; o[0]=f2bf(v0); o[1]=f2bf(v1); o[2]=f2bf(v2); o[3]=f2bf(v3);
        if constexpr (MODE == 0){
          *(u16x4*)((u16*)Cv + cbase + (long long)gm * N + gn) = o;
        } else {
          // brick out: brick ((gm>>4)*nkO + (gn>>5)), quad (gn>>3)&3, row gm&15
          u16* dst = (u16*)Cv + cbase
                   + ((long long)(gm >> 4) * nkO + (gn >> 5)) * 512
                   + ((gn >> 3) & 3) * 128 + (gm & 15) * 8 + (gn & 7);
          *(u16x4*)dst = o;
        }
      }
    }
  }
}

// -------------------------------------------------------- logits + loss -----
__global__ __launch_bounds__(256)
void loss_kernel(const u16* __restrict__ h, const float* __restrict__ cp_w2,
                 const float* __restrict__ cp_b2, const uint32* __restrict__ keep_bits,
                 float* __restrict__ loss)
{
  __shared__ float bl;
  if (threadIdx.x == 0) bl = 0.f;
  __syncthreads();
  const int wv = threadIdx.x >> 6, lane = threadIdx.x & 63;
  const int i  = blockIdx.x * 4 + wv;
  const u16* hr = h + (size_t)i * D_ + lane * 16;
  const uint4 ha = *(const uint4*)(hr);
  const uint4 hb = *(const uint4*)(hr + 8);
  float hx[16];
  hx[0]=bf_lo(ha.x); hx[1]=bf_hi(ha.x); hx[2]=bf_lo(ha.y); hx[3]=bf_hi(ha.y);
  hx[4]=bf_lo(ha.z); hx[5]=bf_hi(ha.z); hx[6]=bf_lo(ha.w); hx[7]=bf_hi(ha.w);
  hx[8]=bf_lo(hb.x); hx[9]=bf_hi(hb.x); hx[10]=bf_lo(hb.y); hx[11]=bf_hi(hb.y);
  hx[12]=bf_lo(hb.z); hx[13]=bf_hi(hb.z); hx[14]=bf_lo(hb.w); hx[15]=bf_hi(hb.w);
  float acc[NEXP];
  #pragma unroll
  for (int e = 0; e < NEXP; e++){
    const float* wr = cp_w2 + e * D_ + lane * 16;
    const float4 w0 = *(const float4*)(wr +  0);
    const float4 w1 = *(const float4*)(wr +  4);
    const float4 w2 = *(const float4*)(wr +  8);
    const float4 w3 = *(const float4*)(wr + 12);
    float s = hx[0]*w0.x + hx[1]*w0.y + hx[2]*w0.z + hx[3]*w0.w;
    s += hx[4]*w1.x + hx[5]*w1.y + hx[6]*w1.z + hx[7]*w1.w;
    s += hx[8]*w2.x + hx[9]*w2.y + hx[10]*w2.z + hx[11]*w2.w;
    s += hx[12]*w3.x + hx[13]*w3.y + hx[14]*w3.z + hx[15]*w3.w;
    acc[e] = s;
  }
  #pragma unroll
  for (int e = 0; e < NEXP; e++){
    #pragma unroll
    for (int off = 32; off >= 1; off >>= 1) acc[e] += __shfl_xor(acc[e], off);
  }
  if (lane == 0){
    const uint32 kb = keep_bits[i];
    float li = 0.f;
    #pragma unroll
    for (int e = 0; e < NEXP; e++){
      const float l  = acc[e] + cp_b2[e];
      const float sp = fmaxf(l, 0.f) + log1pf(expf(-fabsf(l)));
      li += sp - l * (float)((kb >> e) & 1u);
    }
    atomicAdd(&bl, li);
  }
  __syncthreads();
  if (threadIdx.x == 0) atomicAdd(loss, bl);
}

// ------------------------------------------------------------ LN gather -----
// Y in BRICK layout (nk32 = 32): thread t holds cols c=t*4..+3 of row
// slot (b&1023): brick (slot>>4)*32+(t>>3), quad (t>>1)&3, lane-row slot&15.
__global__ __launch_bounds__(256)
void ln_gather_kernel(const float* __restrict__ x, const int* __restrict__ rowlist,
                      const float* __restrict__ ln_g, const float* __restrict__ ln_b,
                      u16* __restrict__ Y)
{
  __shared__ float red[8];
  const int b    = blockIdx.x;
  const int e    = b >> 10;
  const int slot = b & (KCAP - 1);
  const int row  = rowlist[b];
  const int tid  = threadIdx.x;
  const float4 v = *(const float4*)(x + (size_t)row * D_ + tid * 4);
  float s = v.x + v.y + v.z + v.w;
  float q = v.x*v.x + v.y*v.y + v.z*v.z + v.w*v.w;
  const int lane = tid & 63, wv = tid >> 6;
  #pragma unroll
  for (int off = 32; off >= 1; off >>= 1){ s += __shfl_xor(s, off); q += __shfl_xor(q, off); }
  if (lane == 0){ red[wv] = s; red[4 + wv] = q; }
  __syncthreads();
  s = red[0] + red[1] + red[2] + red[3];
  q = red[4] + red[5] + red[6] + red[7];
  const float mu  = s * (1.0f / D_);
  const float var = q * (1.0f / D_) - mu * mu;
  const float rs  = rsqrtf(var + 1e-5f);
  const float4 g  = *(const float4*)(ln_g + tid * 4);
  const float4 bb = *(const float4*)(ln_b + tid * 4);
  u16x4 o;
  o[0] = f2bf((v.x - mu) * rs * g.x + bb.x);
  o[1] = f2bf((v.y - mu) * rs * g.y + bb.y);
  o[2] = f2bf((v.z - mu) * rs * g.z + bb.z);
  o[3] = f2bf((v.w - mu) * rs * g.w + bb.w);
  u16* dst = Y + (size_t)e * KCAP * D_
           + ((size_t)(slot >> 4) * 32 + (tid >> 3)) * 512
           + ((tid >> 1) & 3) * 128 + (slot & 15) * 8 + (tid & 1) * 4;
  *(u16x4*)dst = o;
}

// -------------------------------------------------------------- combine -----
__global__ __launch_bounds__(256)
void combine_kernel(const float* __restrict__ x, const uint32* __restrict__ keep_bits,
                    const int* __restrict__ inv, const float* __restrict__ wlist,
                    const float* __restrict__ P0, const float* __restrict__ P1,
                    const float* __restrict__ b2s, float* __restrict__ out)
{
  const int i = blockIdx.x;
  const int c = threadIdx.x * 4;
  float4 v = *(const float4*)(x + (size_t)i * D_ + c);
  uint32 kb = keep_bits[i];
  while (kb){
    const int e = __ffs(kb) - 1;
    kb &= kb - 1;
    const int r = inv[i * NEXP + e];
    const float w = wlist[e * KCAP + r];
    const size_t ro = ((size_t)(e * KCAP + r)) * D_ + c;
    const float4 p0 = *(const float4*)(P0 + ro);
    const float4 p1 = *(const float4*)(P1 + ro);
    const float4 b2 = *(const float4*)(b2s + (size_t)e * D_ + c);
    v.x += w * (p0.x + p1.x + b2.x);
    v.y += w * (p0.y + p1.y + b2.y);
    v.z += w * (p0.z + p1.z + b2.z);
    v.w += w * (p0.w + p1.w + b2.w);
  }
  *(float4*)(out + (size_t)i * D_ + c) = v;
}

__global__ void finalize_loss_kernel(const float* __restrict__ loss, float* __restrict__ outp){
  outp[0] = loss[0] * (1.0f / (float)(BS_ * NEXP));
}

// ---------------------------------------------------------------- launch ----
extern "C" void kernel_launch(void* const* d_in, const int* in_sizes, int n_in,
                              void* d_out, int out_size, void* d_ws, size_t ws_size,
                              hipStream_t stream)
{
  const float* x     = (const float*)d_in[0];
  const float* Wg    = (const float*)d_in[1];
  const float* cp_w1 = (const float*)d_in[2];
  const float* cp_b1 = (const float*)d_in[3];
  const float* cp_w2 = (const float*)d_in[4];
  const float* cp_b2 = (const float*)d_in[5];
  const float* ln_g  = (const float*)d_in[6];
  const float* ln_b  = (const float*)d_in[7];
  const float* fc1s  = (const float*)d_in[8];
  const float* b1s   = (const float*)d_in[9];
  const float* fc2s  = (const float*)d_in[10];
  const float* b2s   = (const float*)d_in[11];
  float* out = (float*)d_out;

  char* p = (char*)d_ws;
  auto take = [&](size_t bytes) -> char* {
    char* r = p; p += (bytes + 255) & ~(size_t)255; return r;
  };
  float*  scores    = (float*) take((size_t)BS_ * NEXP * 4);
  int*    counts    = (int*)   take(256);
  float*  loss      = (float*) take(256);
  int*    rowlist   = (int*)   take((size_t)BS_ * 4);
  float*  wlist     = (float*) take((size_t)BS_ * 4);
  uint32* keep_bits = (uint32*)take((size_t)BS_ * 4);
  int*    inv       = (int*)   take((size_t)BS_ * NEXP * 4);
  u16*    xh        = (u16*)   take((size_t)BS_ * D_ * 2);            // 16 MB bricks
  u16*    cpw1p     = (u16*)   take((size_t)D_ * D_ * 2);             //  2 MB bricks
  u16*    fc1p      = (u16*)   take((size_t)NEXP * DD_ * D_ * 2);     // 64 MB bricks
  u16*    fc2p      = (u16*)   take((size_t)NEXP * D_ * DD_ * 2);     // 64 MB bricks
  u16*    H1        = (u16*)   take((size_t)NEXP * KCAP * DD_ * 2);   // 64 MB bricks
  u16*    h_cp      = (u16*)   take((size_t)BS_ * D_ * 2);            // 16 MB rowmajor
  u16*    Y         = (u16*)   take((size_t)NEXP * KCAP * D_ * 2);    // 16 MB bricks
  // fc2 split-K fp32 partials (32 MB each) over regions dead by fc2 time:
  float*  Pt0       = (float*)xh;
  float*  Pt1       = (float*)((char*)xh + ((size_t)32 << 20));

  hipMemsetAsync(counts, 0, 512, stream);   // counts + loss

  pack_b_kernel<<<(D_ * D_ / 8) / 256, 256, 0, stream>>>(cp_w1, cpw1p, D_, 5);
  pack_b_kernel<<<(NEXP * DD_ * D_ / 8) / 256, 256, 0, stream>>>(fc1s, fc1p, D_, 5);
  pack_b_kernel<<<(NEXP * D_ * DD_ / 8) / 256, 256, 0, stream>>>(fc2s, fc2p, DD_, 7);

  gating_kernel<<<BS_, 64, 0, stream>>>(x, Wg, scores, keep_bits, xh);

  select_kernel<<<dim3(BS_ / 256, NEXP), 256, 0, stream>>>(
      scores, keep_bits, counts, rowlist, wlist, inv);

  // cp: h = gelu(x @ cp_w1^T + cp_b1)  [8192x1024, K=1024] -> rowmajor bf16
  gemm_br<0, 1><<<dim3(D_ / 128, BS_ / 128, 1), 256, 0, stream>>>(
      xh, cpw1p, cp_b1, h_cp, nullptr, nullptr, BS_, D_, D_, 0, 0, 0, 0);

  loss_kernel<<<BS_ / 4, 256, 0, stream>>>(h_cp, cp_w2, cp_b2, keep_bits, loss);

  ln_gather_kernel<<<BS_, 256, 0, stream>>>(x, rowlist, ln_g, ln_b, Y);

  // fc1: H1[e] = gelu(Y[e] @ fc1s[e]^T + b1s[e]) -> BRICK bf16 (for fc2)
  gemm_br<1, 1><<<dim3(DD_ / 128, KCAP / 128, NEXP), 256, 0, stream>>>(
      Y, fc1p, b1s, H1, nullptr, nullptr, KCAP, DD_, D_,
      (long long)KCAP * D_, (long long)DD_ * D_, DD_, (long long)KCAP * DD_);

  // fc2: partials = H1[e] @ fc2s[e]^T  [1024x1024, K=4096] x8, split-K=2
  gemm_br<2, 2><<<dim3(D_ / 128, KCAP / 128, NEXP * 2), 256, 0, stream>>>(
      H1, fc2p, nullptr, nullptr, Pt0, Pt1, KCAP, D_, DD_,
      (long long)KCAP * DD_, (long long)D_ * DD_, 0, (long long)KCAP * D_);

  combine_kernel<<<BS_, 256, 0, stream>>>(x, keep_bits, inv, wlist, Pt0, Pt1, b2s, out);

  finalize_loss_kernel<<<1, 1, 0, stream>>>(loss, out + (size_t)BS_ * D_);
}

// Round 6
// 849.738 us; speedup vs baseline: 1.0802x; 1.0802x over previous
//
#include <hip/hip_runtime.h>

// DiffMoE fused step, MI355X gfx950. Round 6.
// Changes vs R5:
//  - select: O(N^2) rank-count replaced by exact radix-threshold:
//    hist(bits>>13, 2^19 buckets) -> threshold scan -> members -> classify.
//    Handles fp32-tie + index ordering exactly (matches stable argsort).
//  - gemm_br: BK=64 (2 k-bricks per barrier, half the barrier drains),
//    __launch_bounds__(256,3) to hold 3 blocks/CU. LDS 32 KB/block.

#define BS_   8192
#define D_    1024
#define DD_   4096
#define NEXP  8
#define KCAP  1024

typedef unsigned int   uint32;
typedef unsigned short u16;
typedef __bf16 bf16x8  __attribute__((ext_vector_type(8)));
typedef float  f32x4   __attribute__((ext_vector_type(4)));
typedef u16    u16x8   __attribute__((ext_vector_type(8)));
typedef u16    u16x4   __attribute__((ext_vector_type(4)));

__device__ __forceinline__ u16 f2bf(float f){
  uint32 u = __float_as_uint(f);
  u = (u + 0x7fffu + ((u >> 16) & 1u)) >> 16;   // RNE
  return (u16)u;
}
__device__ __forceinline__ float bf_lo(uint32 u){ return __uint_as_float(u << 16); }
__device__ __forceinline__ float bf_hi(uint32 u){ return __uint_as_float(u & 0xffff0000u); }

__device__ __forceinline__ float gelu_fast(float v){
  const float u2 = v * (1.5957691216057308f + 0.07135481282962162f * v * v);
  const float e  = __expf(u2);
  return v - v / (1.0f + e);
}
__device__ __forceinline__ void glds16(const u16* g, u16* l){
  __builtin_amdgcn_global_load_lds(
      (const __attribute__((address_space(1))) unsigned int*)g,
      (__attribute__((address_space(3))) unsigned int*)l, 16, 0, 0);
}

// ---------------------------------------------------------------- pack B ----
__global__ __launch_bounds__(256)
void pack_b_kernel(const float* __restrict__ in, u16* __restrict__ out,
                   int K, int kshift)
{
  const long long t = (long long)blockIdx.x * 256 + threadIdx.x;
  const int  lane  = (int)(t & 63);
  const long long brick = t >> 6;
  const long long n16 = brick >> kshift;
  const int  k32  = (int)(brick & ((1 << kshift) - 1));
  const float* src = in + (n16 * 16 + (lane & 15)) * (long long)K
                        + k32 * 32 + (lane >> 4) * 8;
  const float4 a = *(const float4*)src;
  const float4 b = *(const float4*)(src + 4);
  u16x8 o;
  o[0]=f2bf(a.x); o[1]=f2bf(a.y); o[2]=f2bf(a.z); o[3]=f2bf(a.w);
  o[4]=f2bf(b.x); o[5]=f2bf(b.y); o[6]=f2bf(b.z); o[7]=f2bf(b.w);
  *(u16x8*)(out + t * 8) = o;
}

// ---------------------------------------------------------------- gating ----
// scoresT[e][i] (transposed for select), keep_bits=0, xh bricks.
__global__ __launch_bounds__(64)
void gating_kernel(const float* __restrict__ x, const float* __restrict__ Wg,
                   float* __restrict__ scoresT, uint32* __restrict__ keep_bits,
                   u16* __restrict__ xh)
{
  const int i    = blockIdx.x;
  const int lane = threadIdx.x;
  const float* xr = x + (size_t)i * D_ + lane * 16;
  const float4 x0 = *(const float4*)(xr +  0);
  const float4 x1 = *(const float4*)(xr +  4);
  const float4 x2 = *(const float4*)(xr +  8);
  const float4 x3 = *(const float4*)(xr + 12);
  u16x8 p0, p1;
  p0[0]=f2bf(x0.x); p0[1]=f2bf(x0.y); p0[2]=f2bf(x0.z); p0[3]=f2bf(x0.w);
  p0[4]=f2bf(x1.x); p0[5]=f2bf(x1.y); p0[6]=f2bf(x1.z); p0[7]=f2bf(x1.w);
  p1[0]=f2bf(x2.x); p1[1]=f2bf(x2.y); p1[2]=f2bf(x2.z); p1[3]=f2bf(x2.w);
  p1[4]=f2bf(x3.x); p1[5]=f2bf(x3.y); p1[6]=f2bf(x3.z); p1[7]=f2bf(x3.w);
  u16* dst = xh + ((size_t)(i >> 4) * 32 + (lane >> 1)) * 512
                + (lane & 1) * 256 + (i & 15) * 8;
  *(u16x8*)dst         = p0;
  *(u16x8*)(dst + 128) = p1;

  float acc[NEXP];
  #pragma unroll
  for (int e = 0; e < NEXP; e++){
    const float* wr = Wg + e * D_ + lane * 16;
    const float4 w0 = *(const float4*)(wr +  0);
    const float4 w1 = *(const float4*)(wr +  4);
    const float4 w2 = *(const float4*)(wr +  8);
    const float4 w3 = *(const float4*)(wr + 12);
    float s = x0.x*w0.x + x0.y*w0.y + x0.z*w0.z + x0.w*w0.w;
    s += x1.x*w1.x + x1.y*w1.y + x1.z*w1.z + x1.w*w1.w;
    s += x2.x*w2.x + x2.y*w2.y + x2.z*w2.z + x2.w*w2.w;
    s += x3.x*w3.x + x3.y*w3.y + x3.z*w3.z + x3.w*w3.w;
    acc[e] = s;
  }
  #pragma unroll
  for (int e = 0; e < NEXP; e++){
    #pragma unroll
    for (int off = 32; off >= 1; off >>= 1) acc[e] += __shfl_xor(acc[e], off);
  }
  if (lane == 0){
    #pragma unroll
    for (int e = 0; e < NEXP; e++) scoresT[e * BS_ + i] = (tanhf(acc[e]) + 1.0f) * 0.5f;
    keep_bits[i] = 0u;
  }
}

// ------------------------------------------------------------- selection ----
// Exact top-KCAP per expert. Keys: (score_bits, -index) desc (stable argsort).
// Phase 1: histogram of bits>>13 (2^19 buckets, scores in (0,1) -> <0x20000).
__global__ __launch_bounds__(256)
void sel_hist(const float* __restrict__ scoresT, uint32* __restrict__ ghist)
{
  const int e = blockIdx.y;
  const int i = blockIdx.x * 256 + threadIdx.x;
  const uint32 bits = __float_as_uint(scoresT[e * BS_ + i]);
  atomicAdd(&ghist[((uint32)e << 19) | (bits >> 13)], 1u);
}

// Phase 2: per-expert top-down scan -> threshold bucket T, need (1..h[T]).
__global__ __launch_bounds__(256)
void sel_thresh(const uint32* __restrict__ ghist, int* __restrict__ meta)
{
  __shared__ uint32 cs[256];
  __shared__ int sh[2];
  const int e = blockIdx.x;
  const uint32* h = ghist + ((uint32)e << 19);
  uint32 s = 0;
  const int base = threadIdx.x * 2048;
  for (int j = 0; j < 2048; j += 4){
    const uint4 v = *(const uint4*)(h + base + j);
    s += v.x + v.y + v.z + v.w;
  }
  cs[threadIdx.x] = s;
  __syncthreads();
  if (threadIdx.x == 0){
    uint32 above = 0; int tc = 0;
    for (int t = 255; t >= 0; t--){
      if (above + cs[t] >= KCAP){ tc = t; break; }
      above += cs[t];
    }
    sh[0] = tc; sh[1] = (int)above;
  }
  __syncthreads();
  const int tc = sh[0];
  const uint32 above = (uint32)sh[1];
  uint32 s2 = 0;
  const int b2 = tc * 2048 + threadIdx.x * 8;
  #pragma unroll
  for (int j = 0; j < 8; j++) s2 += h[b2 + j];
  __syncthreads();
  cs[threadIdx.x] = s2;
  __syncthreads();
  if (threadIdx.x == 0){
    uint32 ab = above; int sc = 0;
    for (int t = 255; t >= 0; t--){
      if (ab + cs[t] >= KCAP){ sc = t; break; }
      ab += cs[t];
    }
    int T = tc * 2048 + sc * 8;
    for (int b = tc * 2048 + sc * 8 + 7; b >= 0; b--){
      const uint32 hb = h[b];
      if (ab + hb >= KCAP){ T = b; break; }
      ab += hb;
    }
    meta[e * 2]     = T;
    meta[e * 2 + 1] = KCAP - (int)ab;   // need from bucket T
  }
}

// Phase 3: collect indices of boundary-bucket members.
__global__ __launch_bounds__(256)
void sel_members(const float* __restrict__ scoresT, const int* __restrict__ meta,
                 int* __restrict__ memcnt, int* __restrict__ memlist)
{
  const int e = blockIdx.y;
  const int i = blockIdx.x * 256 + threadIdx.x;
  const uint32 bits = __float_as_uint(scoresT[e * BS_ + i]);
  if ((int)(bits >> 13) == meta[e * 2]){
    const int s = atomicAdd(&memcnt[e], 1);
    memlist[e * BS_ + s] = i;
  }
}

// Phase 4: classify + emit rowlist/wlist/inv/keep_bits.
__global__ __launch_bounds__(256)
void sel_classify(const float* __restrict__ scoresT, const int* __restrict__ meta,
                  const int* __restrict__ memcnt, const int* __restrict__ memlist,
                  uint32* __restrict__ keep_bits, int* __restrict__ counts,
                  int* __restrict__ rowlist, float* __restrict__ wlist,
                  int* __restrict__ inv)
{
  const int e = blockIdx.y;
  const int i = blockIdx.x * 256 + threadIdx.x;
  const float ms = scoresT[e * BS_ + i];
  const uint32 bits = __float_as_uint(ms);
  const int b = (int)(bits >> 13);
  const int T = meta[e * 2], need = meta[e * 2 + 1];
  bool sel = (b > T);
  if (b == T){
    const int mc = memcnt[e];
    if (mc <= need) sel = true;
    else {
      int cnt = 0;                       // members with larger key than mine
      for (int s = 0; s < mc; s++){
        const int j = memlist[e * BS_ + s];
        const uint32 bj = __float_as_uint(scoresT[e * BS_ + j]);
        if (bj > bits || (bj == bits && j < i)) cnt++;
      }
      sel = (cnt < need);
    }
  }
  if (sel){
    const int slot = atomicAdd(&counts[e], 1);
    rowlist[e * KCAP + slot] = i;
    wlist[e * KCAP + slot]   = ms;
    inv[i * NEXP + e]        = slot;
    atomicOr(&keep_bits[i], 1u << e);
  }
}

// ------------------------------------------------------------------ GEMM ----
// All-brick operands, BK=64: per iter each wave stages 4 A-bricks + 4 B-bricks
// (glds16), one barrier drain, then 16 ds_read_b128 + 32 MFMA, barrier.
// MODE 0: +bias, gelu, bf16 row-major out. MODE 1: +bias, gelu, bf16 brick out.
// MODE 2: split-K fp32 partials to P0/P1.
template<int MODE, int SPLIT>
__global__ __launch_bounds__(256, 3)
void gemm_br(const u16* __restrict__ A, const u16* __restrict__ B,
             const float* __restrict__ bias, void* __restrict__ Cv,
             float* __restrict__ P0, float* __restrict__ P1,
             int M, int N, int K,
             long long sA, long long sB, long long sBias, long long sC)
{
  __shared__ u16 smA[16 * 512];
  __shared__ u16 smB[16 * 512];
  const int zr   = blockIdx.z;
  const int z    = zr / SPLIT, ks = zr % SPLIT;
  const int nk   = K >> 5;                 // k32 bricks total
  const int nkk  = (K >> 6) / SPLIT;       // BK=64 iters this split
  const int it0  = nkk * ks;
  const int m0   = blockIdx.y * 128;
  const int n0   = blockIdx.x * 128;
  const int tid  = threadIdx.x;
  const int lane = tid & 63, wv = tid >> 6;
  const int l15  = lane & 15, quad = lane >> 4;
  const int moff = (wv >> 1) * 64, noff = (wv & 1) * 64;

  const u16* Apk = A + (long long)z * sA + ((long long)(m0 >> 4) + wv * 2) * nk * 512 + lane * 8;
  const u16* Bpk = B + (long long)z * sB + ((long long)(n0 >> 4) + wv * 2) * nk * 512 + lane * 8;
  const long long nstr = (long long)nk * 512;

  f32x4 acc[4][4];
  #pragma unroll
  for (int i = 0; i < 4; i++)
    #pragma unroll
    for (int j = 0; j < 4; j++)
      acc[i][j] = (f32x4){0.f, 0.f, 0.f, 0.f};

  for (int kk = it0; kk < it0 + nkk; kk++){
    const long long kb = (long long)(kk * 2) * 512;
    // brick slot (r, khalf) -> smX[(r*2+khalf)*512]; this wave fills r=wv*2, wv*2+1
    glds16(Apk + kb,              smA + (wv * 4 + 0) * 512);
    glds16(Apk + kb + 512,        smA + (wv * 4 + 1) * 512);
    glds16(Apk + nstr + kb,       smA + (wv * 4 + 2) * 512);
    glds16(Apk + nstr + kb + 512, smA + (wv * 4 + 3) * 512);
    glds16(Bpk + kb,              smB + (wv * 4 + 0) * 512);
    glds16(Bpk + kb + 512,        smB + (wv * 4 + 1) * 512);
    glds16(Bpk + nstr + kb,       smB + (wv * 4 + 2) * 512);
    glds16(Bpk + nstr + kb + 512, smB + (wv * 4 + 3) * 512);
    __syncthreads();
    #pragma unroll
    for (int kh = 0; kh < 2; kh++){
      bf16x8 aF[4], bF[4];
      #pragma unroll
      for (int i = 0; i < 4; i++)
        aF[i] = *(const bf16x8*)(smA + ((((wv >> 1) * 4 + i) * 2 + kh) * 512) + lane * 8);
      #pragma unroll
      for (int j = 0; j < 4; j++)
        bF[j] = *(const bf16x8*)(smB + ((((wv & 1) * 4 + j) * 2 + kh) * 512) + lane * 8);
      #pragma unroll
      for (int i = 0; i < 4; i++)
        #pragma unroll
        for (int j = 0; j < 4; j++)
          acc[i][j] = __builtin_amdgcn_mfma_f32_16x16x32_bf16(bF[j], aF[i], acc[i][j], 0, 0, 0);
    }
    __syncthreads();
  }

  // D^T mapping: acc[i][j] reg r -> (m = m0+moff+i*16+l15, n = n0+noff+j*16+quad*4+r)
  if constexpr (MODE == 2){
    float* Pout = (ks == 0 ? P0 : P1) + (long long)z * sC;
    #pragma unroll
    for (int i = 0; i < 4; i++){
      const int gm = m0 + moff + i * 16 + l15;
      #pragma unroll
      for (int j = 0; j < 4; j++){
        const int gn = n0 + noff + j * 16 + quad * 4;
        *(float4*)(Pout + (long long)gm * N + gn) =
            make_float4(acc[i][j][0], acc[i][j][1], acc[i][j][2], acc[i][j][3]);
      }
    }
  } else {
    const float* biasp = bias + (long long)z * sBias;
    const long long cbase = (long long)z * sC;
    const int nkO = N >> 5;
    #pragma unroll
    for (int i = 0; i < 4; i++){
      const int gm = m0 + moff + i * 16 + l15;
      #pragma unroll
      for (int j = 0; j < 4; j++){
        const int gn = n0 + noff + j * 16 + quad * 4;
        const float4 bv = *(const float4*)(biasp + gn);
        float v0 = gelu_fast(acc[i][j][0] + bv.x);
        float v1 = gelu_fast(acc[i][j][1] + bv.y);
        float v2 = gelu_fast(acc[i][j][2] + bv.z);
        float v3 = gelu_fast(acc[i][j][3] + bv.w);
        u16x4 o; o[0]=f2bf(v0); o[1]=f2bf(v1); o[2]=f2bf(v2); o[3]=f2bf(v3);
        if constexpr (MODE == 0){
          *(u16x4*)((u16*)Cv + cbase + (long long)gm * N + gn) = o;
        } else {
          u16* dst = (u16*)Cv + cbase
                   + ((long long)(gm >> 4) * nkO + (gn >> 5)) * 512
                   + ((gn >> 3) & 3) * 128 + (gm & 15) * 8 + (gn & 7);
          *(u16x4*)dst = o;
        }
      }
    }
  }
}

// -------------------------------------------------------- logits + loss -----
__global__ __launch_bounds__(256)
void loss_kernel(const u16* __restrict__ h, const float* __restrict__ cp_w2,
                 const float* __restrict__ cp_b2, const uint32* __restrict__ keep_bits,
                 float* __restrict__ loss)
{
  __shared__ float bl;
  if (threadIdx.x == 0) bl = 0.f;
  __syncthreads();
  const int wv = threadIdx.x >> 6, lane = threadIdx.x & 63;
  const int i  = blockIdx.x * 4 + wv;
  const u16* hr = h + (size_t)i * D_ + lane * 16;
  const uint4 ha = *(const uint4*)(hr);
  const uint4 hb = *(const uint4*)(hr + 8);
  float hx[16];
  hx[0]=bf_lo(ha.x); hx[1]=bf_hi(ha.x); hx[2]=bf_lo(ha.y); hx[3]=bf_hi(ha.y);
  hx[4]=bf_lo(ha.z); hx[5]=bf_hi(ha.z); hx[6]=bf_lo(ha.w); hx[7]=bf_hi(ha.w);
  hx[8]=bf_lo(hb.x); hx[9]=bf_hi(hb.x); hx[10]=bf_lo(hb.y); hx[11]=bf_hi(hb.y);
  hx[12]=bf_lo(hb.z); hx[13]=bf_hi(hb.z); hx[14]=bf_lo(hb.w); hx[15]=bf_hi(hb.w);
  float acc[NEXP];
  #pragma unroll
  for (int e = 0; e < NEXP; e++){
    const float* wr = cp_w2 + e * D_ + lane * 16;
    const float4 w0 = *(const float4*)(wr +  0);
    const float4 w1 = *(const float4*)(wr +  4);
    const float4 w2 = *(const float4*)(wr +  8);
    const float4 w3 = *(const float4*)(wr + 12);
    float s = hx[0]*w0.x + hx[1]*w0.y + hx[2]*w0.z + hx[3]*w0.w;
    s += hx[4]*w1.x + hx[5]*w1.y + hx[6]*w1.z + hx[7]*w1.w;
    s += hx[8]*w2.x + hx[9]*w2.y + hx[10]*w2.z + hx[11]*w2.w;
    s += hx[12]*w3.x + hx[13]*w3.y + hx[14]*w3.z + hx[15]*w3.w;
    acc[e] = s;
  }
  #pragma unroll
  for (int e = 0; e < NEXP; e++){
    #pragma unroll
    for (int off = 32; off >= 1; off >>= 1) acc[e] += __shfl_xor(acc[e], off);
  }
  if (lane == 0){
    const uint32 kb = keep_bits[i];
    float li = 0.f;
    #pragma unroll
    for (int e = 0; e < NEXP; e++){
      const float l  = acc[e] + cp_b2[e];
      const float sp = fmaxf(l, 0.f) + log1pf(expf(-fabsf(l)));
      li += sp - l * (float)((kb >> e) & 1u);
    }
    atomicAdd(&bl, li);
  }
  __syncthreads();
  if (threadIdx.x == 0) atomicAdd(loss, bl);
}

// ------------------------------------------------------------ LN gather -----
__global__ __launch_bounds__(256)
void ln_gather_kernel(const float* __restrict__ x, const int* __restrict__ rowlist,
                      const float* __restrict__ ln_g, const float* __restrict__ ln_b,
                      u16* __restrict__ Y)
{
  __shared__ float red[8];
  const int b    = blockIdx.x;
  const int e    = b >> 10;
  const int slot = b & (KCAP - 1);
  const int row  = rowlist[b];
  const int tid  = threadIdx.x;
  const float4 v = *(const float4*)(x + (size_t)row * D_ + tid * 4);
  float s = v.x + v.y + v.z + v.w;
  float q = v.x*v.x + v.y*v.y + v.z*v.z + v.w*v.w;
  const int lane = tid & 63, wv = tid >> 6;
  #pragma unroll
  for (int off = 32; off >= 1; off >>= 1){ s += __shfl_xor(s, off); q += __shfl_xor(q, off); }
  if (lane == 0){ red[wv] = s; red[4 + wv] = q; }
  __syncthreads();
  s = red[0] + red[1] + red[2] + red[3];
  q = red[4] + red[5] + red[6] + red[7];
  const float mu  = s * (1.0f / D_);
  const float var = q * (1.0f / D_) - mu * mu;
  const float rs  = rsqrtf(var + 1e-5f);
  const float4 g  = *(const float4*)(ln_g + tid * 4);
  const float4 bb = *(const float4*)(ln_b + tid * 4);
  u16x4 o;
  o[0] = f2bf((v.x - mu) * rs * g.x + bb.x);
  o[1] = f2bf((v.y - mu) * rs * g.y + bb.y);
  o[2] = f2bf((v.z - mu) * rs * g.z + bb.z);
  o[3] = f2bf((v.w - mu) * rs * g.w + bb.w);
  u16* dst = Y + (size_t)e * KCAP * D_
           + ((size_t)(slot >> 4) * 32 + (tid >> 3)) * 512
           + ((tid >> 1) & 3) * 128 + (slot & 15) * 8 + (tid & 1) * 4;
  *(u16x4*)dst = o;
}

// -------------------------------------------------------------- combine -----
__global__ __launch_bounds__(256)
void combine_kernel(const float* __restrict__ x, const uint32* __restrict__ keep_bits,
                    const int* __restrict__ inv, const float* __restrict__ wlist,
                    const float* __restrict__ P0, const float* __restrict__ P1,
                    const float* __restrict__ b2s, float* __restrict__ out)
{
  const int i = blockIdx.x;
  const int c = threadIdx.x * 4;
  float4 v = *(const float4*)(x + (size_t)i * D_ + c);
  uint32 kb = keep_bits[i];
  while (kb){
    const int e = __ffs(kb) - 1;
    kb &= kb - 1;
    const int r = inv[i * NEXP + e];
    const float w = wlist[e * KCAP + r];
    const size_t ro = ((size_t)(e * KCAP + r)) * D_ + c;
    const float4 p0 = *(const float4*)(P0 + ro);
    const float4 p1 = *(const float4*)(P1 + ro);
    const float4 b2 = *(const float4*)(b2s + (size_t)e * D_ + c);
    v.x += w * (p0.x + p1.x + b2.x);
    v.y += w * (p0.y + p1.y + b2.y);
    v.z += w * (p0.z + p1.z + b2.z);
    v.w += w * (p0.w + p1.w + b2.w);
  }
  *(float4*)(out + (size_t)i * D_ + c) = v;
}

__global__ void finalize_loss_kernel(const float* __restrict__ loss, float* __restrict__ outp){
  outp[0] = loss[0] * (1.0f / (float)(BS_ * NEXP));
}

// ---------------------------------------------------------------- launch ----
extern "C" void kernel_launch(void* const* d_in, const int* in_sizes, int n_in,
                              void* d_out, int out_size, void* d_ws, size_t ws_size,
                              hipStream_t stream)
{
  const float* x     = (const float*)d_in[0];
  const float* Wg    = (const float*)d_in[1];
  const float* cp_w1 = (const float*)d_in[2];
  const float* cp_b1 = (const float*)d_in[3];
  const float* cp_w2 = (const float*)d_in[4];
  const float* cp_b2 = (const float*)d_in[5];
  const float* ln_g  = (const float*)d_in[6];
  const float* ln_b  = (const float*)d_in[7];
  const float* fc1s  = (const float*)d_in[8];
  const float* b1s   = (const float*)d_in[9];
  const float* fc2s  = (const float*)d_in[10];
  const float* b2s   = (const float*)d_in[11];
  float* out = (float*)d_out;

  char* p = (char*)d_ws;
  auto take = [&](size_t bytes) -> char* {
    char* r = p; p += (bytes + 255) & ~(size_t)255; return r;
  };
  float*  scoresT   = (float*) take((size_t)BS_ * NEXP * 4);
  int*    counts    = (int*)   take(256);                    // memset block A
  float*  loss      = (float*) take(256);                    //   (768 B total)
  int*    meta      = (int*)   take(256);                    //   T,need x8 + memcnt x8
  int*    rowlist   = (int*)   take((size_t)BS_ * 4);
  float*  wlist     = (float*) take((size_t)BS_ * 4);
  uint32* keep_bits = (uint32*)take((size_t)BS_ * 4);
  int*    inv       = (int*)   take((size_t)BS_ * NEXP * 4);
  u16*    xh        = (u16*)   take((size_t)BS_ * D_ * 2);            // 16 MB bricks
  u16*    cpw1p     = (u16*)   take((size_t)D_ * D_ * 2);             //  2 MB bricks
  u16*    fc1p      = (u16*)   take((size_t)NEXP * DD_ * D_ * 2);     // 64 MB bricks
  u16*    fc2p      = (u16*)   take((size_t)NEXP * D_ * DD_ * 2);     // 64 MB bricks
  u16*    H1        = (u16*)   take((size_t)NEXP * KCAP * DD_ * 2);   // 64 MB bricks
  u16*    h_cp      = (u16*)   take((size_t)BS_ * D_ * 2);            // 16 MB rowmajor
  u16*    Y         = (u16*)   take((size_t)NEXP * KCAP * D_ * 2);    // 16 MB bricks
  int*    memcnt    = meta + 16;
  // ghist (16 MB) + memlist (256 KB) aliased over H1 (dead until fc1);
  // fc2 split-K partials aliased over xh.. region (dead by fc2 time).
  uint32* ghist     = (uint32*)H1;
  int*    memlist   = (int*)((char*)H1 + ((size_t)16 << 20));
  float*  Pt0       = (float*)xh;
  float*  Pt1       = (float*)((char*)xh + ((size_t)32 << 20));

  hipMemsetAsync(counts, 0, 768, stream);                    // counts+loss+meta
  hipMemsetAsync(ghist, 0, (size_t)16 << 20, stream);        // histogram

  pack_b_kernel<<<(D_ * D_ / 8) / 256, 256, 0, stream>>>(cp_w1, cpw1p, D_, 5);
  pack_b_kernel<<<(NEXP * DD_ * D_ / 8) / 256, 256, 0, stream>>>(fc1s, fc1p, D_, 5);
  pack_b_kernel<<<(NEXP * D_ * DD_ / 8) / 256, 256, 0, stream>>>(fc2s, fc2p, DD_, 7);

  gating_kernel<<<BS_, 64, 0, stream>>>(x, Wg, scoresT, keep_bits, xh);

  sel_hist    <<<dim3(BS_ / 256, NEXP), 256, 0, stream>>>(scoresT, ghist);
  sel_thresh  <<<NEXP, 256, 0, stream>>>(ghist, meta);
  sel_members <<<dim3(BS_ / 256, NEXP), 256, 0, stream>>>(scoresT, meta, memcnt, memlist);
  sel_classify<<<dim3(BS_ / 256, NEXP), 256, 0, stream>>>(
      scoresT, meta, memcnt, memlist, keep_bits, counts, rowlist, wlist, inv);

  // cp: h = gelu(x @ cp_w1^T + cp_b1)  [8192x1024, K=1024] -> rowmajor bf16
  gemm_br<0, 1><<<dim3(D_ / 128, BS_ / 128, 1), 256, 0, stream>>>(
      xh, cpw1p, cp_b1, h_cp, nullptr, nullptr, BS_, D_, D_, 0, 0, 0, 0);

  loss_kernel<<<BS_ / 4, 256, 0, stream>>>(h_cp, cp_w2, cp_b2, keep_bits, loss);

  ln_gather_kernel<<<BS_, 256, 0, stream>>>(x, rowlist, ln_g, ln_b, Y);

  // fc1: H1[e] = gelu(Y[e] @ fc1s[e]^T + b1s[e]) -> brick bf16
  gemm_br<1, 1><<<dim3(DD_ / 128, KCAP / 128, NEXP), 256, 0, stream>>>(
      Y, fc1p, b1s, H1, nullptr, nullptr, KCAP, DD_, D_,
      (long long)KCAP * D_, (long long)DD_ * D_, DD_, (long long)KCAP * DD_);

  // fc2: partials = H1[e] @ fc2s[e]^T  [1024x1024, K=4096] x8, split-K=2
  gemm_br<2, 2><<<dim3(D_ / 128, KCAP / 128, NEXP * 2), 256, 0, stream>>>(
      H1, fc2p, nullptr, nullptr, Pt0, Pt1, KCAP, D_, DD_,
      (long long)KCAP * DD_, (long long)D_ * DD_, 0, (long long)KCAP * D_);

  combine_kernel<<<BS_, 256, 0, stream>>>(x, keep_bits, inv, wlist, Pt0, Pt1, b2s, out);

  finalize_loss_kernel<<<1, 1, 0, stream>>>(loss, out + (size_t)BS_ * D_);
}